// Round 32
// baseline (529.057 us; speedup 1.0000x reference)
//
#include <hip/hip_runtime.h>

// ---------------------------------------------------------------------------
// FreeFlowFPN. Inputs fp32, OUTPUT FP32. R31 = 527us (conv 270 + non-conv 257).
// Conv: T14 reg-prefetch proven (+31us). Remaining stall = the post-MFMA
// barrier protecting single-buffered LDS. THIS ROUND (one change): LDS
// double-buffer (Asm/Bsm x2, 62.5KB) -> ONE barrier per K-step (72 vs 144);
// iter i: write buf[i&1] -> barrier -> prefetch k0+32 -> MFMA from buf[i&1].
// Correctness: iter i's barrier separates iter i-1 reads from iter i+1 writes.
// Everything else byte-identical to R31.
// ---------------------------------------------------------------------------

#define OFF1 16777216      // 256*256*256
#define OFF2 20971520      // OFF1 + 256*128*128
#define OFF3 22020096      // OFF2 + 256*64*64
#define TOTELEM 22282240   // OFF3 + 256*32*32
#define WTOT 589824        // 256*256*9 weights per level
#define TAU 0.1f
#define HDR 2048           // ws header floats (8KB)

typedef unsigned short u16;
typedef short bf16x8 __attribute__((ext_vector_type(8)));
typedef float f32x4 __attribute__((ext_vector_type(4)));

__device__ __forceinline__ size_t lvl_off(int l) {
    return (l == 0) ? 0 : (l == 1) ? (size_t)OFF1 : (l == 2) ? (size_t)OFF2 : (size_t)OFF3;
}
__device__ __forceinline__ u16 f2bf(float f) {   // RNE
    unsigned u = __float_as_uint(f);
    u += 0x7FFFu + ((u >> 16) & 1u);
    return (u16)(u >> 16);
}

// bilinear sample (fp32), torch align_corners=False (rows then cols)
__device__ __forceinline__ float bilin_sample(const float* __restrict__ srcLvl,
                                              int logHs, int c, int y, int x, int logHt) {
    int Hs = 1 << logHs;
    float scale = (float)Hs / (float)(1 << logHt);
    float sy = fminf(fmaxf(((float)y + 0.5f) * scale - 0.5f, 0.f), (float)(Hs - 1));
    float sx = fminf(fmaxf(((float)x + 0.5f) * scale - 0.5f, 0.f), (float)(Hs - 1));
    int y0 = (int)sy, x0 = (int)sx;
    int y1 = min(y0 + 1, Hs - 1), x1 = min(x0 + 1, Hs - 1);
    float fy = sy - (float)y0, fx = sx - (float)x0;
    const float* sp = srcLvl + ((size_t)c << (2 * logHs));
    float v00 = sp[(size_t)(y0 << logHs) + x0], v01 = sp[(size_t)(y0 << logHs) + x1];
    float v10 = sp[(size_t)(y1 << logHs) + x0], v11 = sp[(size_t)(y1 << logHs) + x1];
    float r0 = v00 * (1.f - fy) + v10 * fy;
    float r1 = v01 * (1.f - fy) + v11 * fy;
    return r0 * (1.f - fx) + r1 * fx;
}

__global__ void marker_kernel(float* __restrict__ out, float v) {
    if (threadIdx.x == 0 && blockIdx.x == 0) out[0] = v;
}

// ---------------- GAP ----------------
__global__ void gap_kernel(const float* __restrict__ f0, const float* __restrict__ f1,
                           const float* __restrict__ f2, const float* __restrict__ f3,
                           float* __restrict__ vecs) {
    int lb = blockIdx.x;
    int level = lb >> 8, c = lb & 255;
    const float* f; int H;
    switch (level) {
        case 0: f = f0; H = 256; break;
        case 1: f = f1; H = 128; break;
        case 2: f = f2; H = 64;  break;
        default: f = f3; H = 32; break;
    }
    int HW = H * H;
    const float* src = f + (size_t)c * HW;
    float s = 0.f;
    for (int i = threadIdx.x; i < HW; i += 256) s += src[i];
    #pragma unroll
    for (int o = 32; o; o >>= 1) s += __shfl_down(s, o);
    __shared__ float red[4];
    int lane = threadIdx.x & 63, wv = threadIdx.x >> 6;
    if (lane == 0) red[wv] = s;
    __syncthreads();
    if (threadIdx.x == 0)
        vecs[level * 256 + c] = (red[0] + red[1] + red[2] + red[3]) / (float)HW;
}

// ---------------- prep ----------------
__global__ void prep_kernel(const float* __restrict__ vecs_g,
                            const float* __restrict__ mlp_w1, const float* __restrict__ mlp_b1,
                            const float* __restrict__ mlp_w2, const float* __restrict__ mlp_b2,
                            const float* __restrict__ qk_w, const float* __restrict__ qk_b,
                            int* __restrict__ order_g, float* __restrict__ wmat_g) {
    __shared__ float vecs[4][256];
    __shared__ float h[4][64];
    __shared__ float scores[4];
    __shared__ float qk[4][512];
    __shared__ float attnS[4][4];
    int t = threadIdx.x;
    for (int i = t; i < 1024; i += 256) vecs[i >> 8][i & 255] = vecs_g[i];
    __syncthreads();
    {
        int l = t >> 6, j = t & 63;
        float s = mlp_b1[j];
        for (int c = 0; c < 256; c++) s += vecs[l][c] * mlp_w1[c * 64 + j];
        h[l][j] = fmaxf(s, 0.f);
    }
    __syncthreads();
    if (t < 4) {
        float s = mlp_b2[0];
        for (int j = 0; j < 64; j++) s += h[t][j] * mlp_w2[j];
        scores[t] = s;
    }
    __syncthreads();
    if (t == 0) {
        bool used[4] = {false, false, false, false};
        for (int r = 0; r < 4; r++) {
            int best = -1; float bv = 0.f;
            for (int l = 0; l < 4; l++)
                if (!used[l] && (best < 0 || scores[l] > bv)) { best = l; bv = scores[l]; }
            used[best] = true;
            order_g[r] = best;
        }
    }
    for (int idx = t; idx < 2048; idx += 256) {
        int l = idx >> 9, col = idx & 511;
        float s = qk_b[col];
        for (int c = 0; c < 256; c++) s += vecs[l][c] * qk_w[c * 512 + col];
        qk[l][col] = s;
    }
    __syncthreads();
    if (t < 16) {
        int i = t >> 2, j = t & 3;
        float s = 0.f;
        for (int c = 0; c < 256; c++) s += qk[i][c] * qk[j][256 + c];
        attnS[i][j] = s * 0.0625f;
    }
    __syncthreads();
    if (t < 4) {
        int i = t;
        float m = -1e30f;
        for (int j = 0; j < 4; j++) if (j != i) m = fmaxf(m, attnS[i][j]);
        float e[4]; float sum = 0.f;
        for (int j = 0; j < 4; j++) {
            e[j] = (j == i) ? 0.f : expf(attnS[i][j] - m);
            sum += e[j];
        }
        for (int j = 0; j < 4; j++) {
            float p = e[j] / sum;
            wmat_g[i * 4 + j] = (p >= TAU) ? p : 0.f;
        }
    }
}

// ---------------- weight convert (fp32 -> bf16), 8 elems/thread ----------------
__global__ void wconv_kernel(const float* __restrict__ w, u16* __restrict__ dst) {
    long long g = ((long long)blockIdx.x * 256 + threadIdx.x) * 8;
    if (g >= WTOT) return;
    float4 a = *(const float4*)&w[g];
    float4 b = *(const float4*)&w[g + 4];
    uint4 o;
    o.x = ((unsigned)f2bf(a.y) << 16) | f2bf(a.x);
    o.y = ((unsigned)f2bf(a.w) << 16) | f2bf(a.z);
    o.z = ((unsigned)f2bf(b.y) << 16) | f2bf(b.x);
    o.w = ((unsigned)f2bf(b.w) << 16) | f2bf(b.z);
    *(uint4*)&dst[g] = o;
}

// ---------------- G-scheme fusion phase 1, x4 vectorized -----------------------
__global__ void fuse_build_kernel(const float* __restrict__ f0, const float* __restrict__ f1,
                                  const float* __restrict__ f2, const float* __restrict__ f3,
                                  float* __restrict__ fused, const int* __restrict__ order_g,
                                  const float* __restrict__ wmat, int rank) {
    int t = order_g[rank] & 3;
    int logHt = 8 - t, Ht = 1 << logHt;
    int nVec = (256 << (2 * logHt)) >> 2;
    int v = blockIdx.x * 256 + threadIdx.x;
    if (v >= nVec) return;
    int e = v << 2;
    int c = e >> (2 * logHt);
    int p = e & ((1 << (2 * logHt)) - 1);
    int y = p >> logHt, x0 = p & (Ht - 1);
    const float* fr = (t == 0) ? f0 : (t == 1) ? f1 : (t == 2) ? f2 : f3;
    float4 a4 = *(const float4*)&fr[e];
    float av[4] = {a4.x, a4.y, a4.z, a4.w};
    for (int r = 0; r < rank; r++) {
        int s = order_g[r] & 3;
        float w = wmat[s * 4 + t];
        if (w == 0.f) continue;
        const float* src = fused + lvl_off(s);
        #pragma unroll
        for (int j = 0; j < 4; j++)
            av[j] += w * bilin_sample(src, 8 - s, c, y, x0 + j, logHt);
    }
    *(float4*)&fused[lvl_off(t) + e] = make_float4(av[0], av[1], av[2], av[3]);
}

// ---------------- G-scheme fusion phase 2, x4 vectorized -----------------------
__global__ void fuse_final_kernel(float* __restrict__ fused, const int* __restrict__ order_g,
                                  const float* __restrict__ wmat, int rank) {
    int t = order_g[rank] & 3;
    int logHt = 8 - t, Ht = 1 << logHt;
    int nVec = (256 << (2 * logHt)) >> 2;
    int v = blockIdx.x * 256 + threadIdx.x;
    if (v >= nVec) return;
    int e = v << 2;
    int c = e >> (2 * logHt);
    int p = e & ((1 << (2 * logHt)) - 1);
    int y = p >> logHt, x0 = p & (Ht - 1);
    float av[4] = {0.f, 0.f, 0.f, 0.f};
    bool any = false;
    for (int r = rank + 1; r < 4; r++) {
        int s = order_g[r] & 3;
        float w = wmat[s * 4 + t];
        if (w == 0.f) continue;
        any = true;
        const float* src = fused + lvl_off(s);
        #pragma unroll
        for (int j = 0; j < 4; j++)
            av[j] += w * bilin_sample(src, 8 - s, c, y, x0 + j, logHt);
    }
    if (!any) return;
    size_t idx = lvl_off(t) + e;
    float4 cur = *(const float4*)&fused[idx];
    cur.x += av[0]; cur.y += av[1]; cur.z += av[2]; cur.w += av[3];
    *(float4*)&fused[idx] = cur;
}

// ---------------- MFMA conv: 256cout x 128px, dbuf LDS + reg prefetch ----------
template <bool USE_WB16>
__global__ __launch_bounds__(512, 2) void conv_mfma_kernel(
        const float* __restrict__ pyr, float* __restrict__ outb,
        const float* __restrict__ w0, const float* __restrict__ w1,
        const float* __restrict__ w2, const float* __restrict__ w3,
        const u16* __restrict__ wgtB,
        const float* __restrict__ b0, const float* __restrict__ b1,
        const float* __restrict__ b2, const float* __restrict__ b3) {
    int pt = blockIdx.y;   // L0 [0,512) L1 [512,640) L2 [640,672) L3 [672,680)
    int H, logW, nBase, lvl;
    size_t off;
    const float *wgt, *bias;
    if (pt < 512)      { H = 256; logW = 8; off = 0;    lvl = 0; wgt = w0; bias = b0; nBase = pt << 7; }
    else if (pt < 640) { H = 128; logW = 7; off = OFF1; lvl = 1; wgt = w1; bias = b1; nBase = (pt - 512) << 7; }
    else if (pt < 672) { H = 64;  logW = 6; off = OFF2; lvl = 2; wgt = w2; bias = b2; nBase = (pt - 640) << 7; }
    else               { H = 32;  logW = 5; off = OFF3; lvl = 3; wgt = w3; bias = b3; nBase = (pt - 672) << 7; }
    const int W = H, HW = H * W;
    const float* in = pyr + off;
    const u16* wB = USE_WB16 ? (wgtB + (size_t)lvl * WTOT) : nullptr;
    float* out = outb + off;

    __shared__ short Asm[2][256][40];
    __shared__ short Bsm[2][128][40];
    __shared__ float biasS[256];

    int tid = threadIdx.x;
    int lane = tid & 63, wave = tid >> 6;
    int wr = wave >> 1, wc = wave & 1;     // cout quadrant, px half
    int lm = lane & 15;
    int lkg = lane >> 4;

    if (tid < 256) biasS[tid] = bias[tid];

    int pxB = tid & 127;
    int kkBase = (tid >> 7) << 3;          // 0,8,16,24
    int pxAbs = nBase + pxB;
    int yB = pxAbs >> logW, xB = pxAbs & (W - 1);

    int aRow0 = tid >> 3;
    int aKk4 = (tid & 7) << 2;

    uint2 aReg[4];
    float bReg[8];

    #define LOAD_A(K0)                                                          \
        {                                                                       \
            _Pragma("unroll")                                                   \
            for (int p = 0; p < 4; p++) {                                       \
                int row = aRow0 + p * 64;                                       \
                if (USE_WB16) {                                                 \
                    aReg[p] = *(const uint2*)&wB[(size_t)row * 2304 + (K0) + aKk4]; \
                } else {                                                        \
                    float4 v = *(const float4*)&wgt[(size_t)row * 2304 + (K0) + aKk4]; \
                    aReg[p].x = ((unsigned)f2bf(v.y) << 16) | f2bf(v.x);        \
                    aReg[p].y = ((unsigned)f2bf(v.w) << 16) | f2bf(v.z);        \
                }                                                               \
            }                                                                   \
        }
    #define LOAD_B(K0)                                                          \
        {                                                                       \
            int k = (K0) + kkBase;                                              \
            int ci = k / 9, r = k - ci * 9;                                     \
            _Pragma("unroll")                                                   \
            for (int u = 0; u < 8; u++) {                                       \
                int r3 = (r * 11) >> 5;                                         \
                int dy = r3 - 1, dx = r - r3 * 3 - 1;                           \
                int yy = yB + dy, xx = xB + dx;                                 \
                float v = 0.f;                                                  \
                if (yy >= 0 && yy < H && xx >= 0 && xx < W)                     \
                    v = in[(size_t)ci * HW + yy * W + xx];                      \
                bReg[u] = v;                                                    \
                r++;                                                            \
                if (r == 9) { r = 0; ci++; }                                    \
            }                                                                   \
        }

    f32x4 acc[4][4];
    #pragma unroll
    for (int i = 0; i < 4; i++)
        #pragma unroll
        for (int j = 0; j < 4; j++) acc[i][j] = (f32x4){0.f, 0.f, 0.f, 0.f};

    LOAD_A(0);
    LOAD_B(0);

    int buf = 0;
    for (int k0 = 0; k0 < 2304; k0 += 32) {
        // ---- write staged regs to LDS buf
        #pragma unroll
        for (int p = 0; p < 4; p++)
            *(uint2*)&Asm[buf][aRow0 + p * 64][aKk4] = aReg[p];
        {
            unsigned bw[4];
            #pragma unroll
            for (int u = 0; u < 8; u++) {
                unsigned b = f2bf(bReg[u]);
                if (u & 1) bw[u >> 1] |= b << 16; else bw[u >> 1] = b;
            }
            *(uint4*)&Bsm[buf][pxB][kkBase] = make_uint4(bw[0], bw[1], bw[2], bw[3]);
        }
        __syncthreads();   // single barrier per K-step (dbuf)

        // ---- prefetch next K-step (latency hides under MFMA)
        if (k0 + 32 < 2304) {
            LOAD_A(k0 + 32);
            LOAD_B(k0 + 32);
        }

        // ---- fragments + 16 MFMA per wave
        bf16x8 af[4], bfr[4];
        #pragma unroll
        for (int fm = 0; fm < 4; fm++)
            af[fm] = *(const bf16x8*)&Asm[buf][wr * 64 + fm * 16 + lm][lkg * 8];
        #pragma unroll
        for (int fc = 0; fc < 4; fc++)
            bfr[fc] = *(const bf16x8*)&Bsm[buf][wc * 64 + fc * 16 + lm][lkg * 8];
        #pragma unroll
        for (int fm = 0; fm < 4; fm++)
            #pragma unroll
            for (int fc = 0; fc < 4; fc++)
                acc[fm][fc] = __builtin_amdgcn_mfma_f32_16x16x32_bf16(
                    af[fm], bfr[fc], acc[fm][fc], 0, 0, 0);
        buf ^= 1;
    }
    #undef LOAD_A
    #undef LOAD_B

    // epilogue (C layout HW-verified: row=(l>>4)*4+reg, col=l&15)
    #pragma unroll
    for (int fm = 0; fm < 4; fm++) {
        #pragma unroll
        for (int reg = 0; reg < 4; reg++) {
            int row = wr * 64 + fm * 16 + lkg * 4 + reg;
            float bi = biasS[row];
            float* op = out + (size_t)row * HW + nBase;
            #pragma unroll
            for (int fc = 0; fc < 4; fc++) {
                int col = wc * 64 + fc * 16 + lm;
                op[col] = fmaxf(acc[fm][fc][reg] + bi, 0.f);
            }
        }
    }
}

// ================= tier-C fallback (R19's proven fp32 VALU path) ===============
__global__ void pyr_init_kernel(const float* __restrict__ f0, const float* __restrict__ f1,
                                const float* __restrict__ f2, const float* __restrict__ f3,
                                float* __restrict__ pyr) {
    long long e = (long long)blockIdx.x * 256 + threadIdx.x;
    if (e >= TOTELEM) return;
    float v;
    if (e < OFF1)      v = f0[e];
    else if (e < OFF2) v = f1[e - OFF1];
    else if (e < OFF3) v = f2[e - OFF2];
    else               v = f3[e - OFF3];
    pyr[e] = v;
}

__global__ void fuse_step_kernel(float* __restrict__ pyr, const int* __restrict__ order_g,
                                 const float* __restrict__ wmat, int oi, int oj) {
    int a = order_g[oi] & 3, b = order_g[oj] & 3;
    if (a == b) return;
    float w = wmat[a * 4 + b];
    if (w == 0.f) return;
    int logHb = 8 - b, Hb = 1 << logHb;
    int nElem = 256 << (2 * logHb);
    int e = blockIdx.x * 256 + threadIdx.x;
    if (e >= nElem) return;
    int c = e >> (2 * logHb);
    int p = e & ((1 << (2 * logHb)) - 1);
    int y = p >> logHb, x = p & (Hb - 1);
    float val = bilin_sample(pyr + lvl_off(a), 8 - a, c, y, x, logHb);
    pyr[lvl_off(b) + e] += w * val;
}

__global__ __launch_bounds__(256, 2) void conv_strip_kernel(
        const float* __restrict__ in, float* __restrict__ stage,
        int H, int logW, int pixBase, int stripPix,
        const float* __restrict__ wgt, const float* __restrict__ bias) {
    const int W = H, HW = H * W;
    int nAbs = pixBase + blockIdx.y * 256;

    __shared__ float As[8][132];
    __shared__ float Bs[8][256];
    int tid = threadIdx.x;
    int tm = tid >> 4, tn = tid & 15;
    int coutBase = blockIdx.x * 128;
    int pixS = nAbs + tid;
    int yS = pixS >> logW, xS = pixS & (W - 1);

    float acc[8][16];
    #pragma unroll
    for (int i = 0; i < 8; i++)
        #pragma unroll
        for (int j = 0; j < 16; j++) acc[i][j] = 0.f;

    for (int k0 = 0; k0 < 2304; k0 += 8) {
        #pragma unroll
        for (int u = 0; u < 4; u++) {
            int co = (tid >> 3) + u * 32;
            int kk = tid & 7;
            As[kk][co] = wgt[(size_t)(coutBase + co) * 2304 + k0 + kk];
        }
        #pragma unroll
        for (int u = 0; u < 8; u++) {
            int k = k0 + u;
            int ci = k / 9, r = k - ci * 9;
            int rr = r / 3;
            int dy = rr - 1, dx = r - rr * 3 - 1;
            int yy = yS + dy, xx = xS + dx;
            float v = 0.f;
            if (yy >= 0 && yy < H && xx >= 0 && xx < W)
                v = in[(size_t)ci * HW + yy * W + xx];
            Bs[u][tid] = v;
        }
        __syncthreads();
        #pragma unroll
        for (int kk = 0; kk < 8; kk++) {
            float a[8], b[16];
            *(float4*)&a[0] = *(const float4*)&As[kk][tm * 8];
            *(float4*)&a[4] = *(const float4*)&As[kk][tm * 8 + 4];
            *(float4*)&b[0]  = *(const float4*)&Bs[kk][tn * 4];
            *(float4*)&b[4]  = *(const float4*)&Bs[kk][64 + tn * 4];
            *(float4*)&b[8]  = *(const float4*)&Bs[kk][128 + tn * 4];
            *(float4*)&b[12] = *(const float4*)&Bs[kk][192 + tn * 4];
            #pragma unroll
            for (int i = 0; i < 8; i++)
                #pragma unroll
                for (int j = 0; j < 16; j++)
                    acc[i][j] = fmaf(a[i], b[j], acc[i][j]);
        }
        __syncthreads();
    }
    int nLoc = nAbs - pixBase;
    #pragma unroll
    for (int i = 0; i < 8; i++) {
        int co = coutBase + tm * 8 + i;
        float bi = bias[co];
        float* op = stage + (size_t)co * stripPix + nLoc;
        #pragma unroll
        for (int ch = 0; ch < 4; ch++) {
            float4 o;
            o.x = fmaxf(acc[i][ch * 4 + 0] + bi, 0.f);
            o.y = fmaxf(acc[i][ch * 4 + 1] + bi, 0.f);
            o.z = fmaxf(acc[i][ch * 4 + 2] + bi, 0.f);
            o.w = fmaxf(acc[i][ch * 4 + 3] + bi, 0.f);
            *(float4*)(op + ch * 64 + tn * 4) = o;
        }
    }
}

__global__ void copyback_kernel(float* __restrict__ dst, const float* __restrict__ stage,
                                int stripPix, int pixBase, int HW) {
    int gid = blockIdx.x * 256 + threadIdx.x;
    int q = stripPix >> 2;
    int total = q << 8;
    if (gid >= total) return;
    int c = gid / q, rem = gid - c * q;
    float4 v = ((const float4*)stage)[(size_t)c * q + rem];
    ((float4*)(dst + (size_t)c * HW + pixBase))[rem] = v;
}

extern "C" void kernel_launch(void* const* d_in, const int* in_sizes, int n_in,
                              void* d_out, int out_size, void* d_ws, size_t ws_size,
                              hipStream_t stream) {
    const float* f0 = (const float*)d_in[0];
    const float* f1 = (const float*)d_in[1];
    const float* f2 = (const float*)d_in[2];
    const float* f3 = (const float*)d_in[3];
    float* out = (float*)d_out;

    int wi[4], bx[4];
    if (n_in >= 18 && in_sizes[11] == 256) {
        for (int l = 0; l < 4; l++) { wi[l] = 10 + 2 * l; bx[l] = 11 + 2 * l; }
    } else {
        for (int l = 0; l < 4; l++) { wi[l] = 10 + l; bx[l] = 14 + l; }
    }
    const float* cw[4] = {(const float*)d_in[wi[0]], (const float*)d_in[wi[1]],
                          (const float*)d_in[wi[2]], (const float*)d_in[wi[3]]};
    const float* cb[4] = {(const float*)d_in[bx[0]], (const float*)d_in[bx[1]],
                          (const float*)d_in[bx[2]], (const float*)d_in[bx[3]]};

    if (ws_size < (size_t)HDR * 4) {
        size_t kb = ws_size / 1024; if (kb > 7) kb = 7;
        marker_kernel<<<1, 64, 0, stream>>>(out, 49152.f + (float)kb * 128.f);
        return;
    }

    float* wsf = (float*)d_ws;
    float* vecs = wsf;
    int* order = (int*)(wsf + 1024);
    float* wmat = wsf + 1040;

    gap_kernel<<<1024, 256, 0, stream>>>(f0, f1, f2, f3, vecs);
    prep_kernel<<<1, 256, 0, stream>>>(vecs,
        (const float*)d_in[4], (const float*)d_in[5], (const float*)d_in[6],
        (const float*)d_in[7], (const float*)d_in[8], (const float*)d_in[9],
        order, wmat);

    size_t needA0 = (size_t)HDR * 4 + (size_t)TOTELEM * 4;
    size_t needA1 = needA0 + (size_t)4 * WTOT * 2;   // + bf16 weights (4.7MB)

    if (ws_size >= needA0) {
        // ---- tier A: fp32 G-scheme fusion (x4 vec) in ws -> MFMA conv -> d_out
        float* pyr = wsf + HDR;
        for (int k = 0; k < 4; k++)
            fuse_build_kernel<<<16384, 256, 0, stream>>>(f0, f1, f2, f3,
                                                         pyr, order, wmat, k);
        for (int k = 0; k < 3; k++)
            fuse_final_kernel<<<16384, 256, 0, stream>>>(pyr, order, wmat, k);

        if (ws_size >= needA1) {
            u16* wgtB = (u16*)(pyr + (size_t)TOTELEM);
            for (int l = 0; l < 4; l++)
                wconv_kernel<<<WTOT / 8 / 256, 256, 0, stream>>>(cw[l],
                    wgtB + (size_t)l * WTOT);
            conv_mfma_kernel<true><<<dim3(1, 680), 512, 0, stream>>>(
                pyr, out, cw[0], cw[1], cw[2], cw[3], wgtB,
                cb[0], cb[1], cb[2], cb[3]);
        } else {
            conv_mfma_kernel<false><<<dim3(1, 680), 512, 0, stream>>>(
                pyr, out, cw[0], cw[1], cw[2], cw[3], (const u16*)nullptr,
                cb[0], cb[1], cb[2], cb[3]);
        }
        return;
    }

    if (ws_size >= (size_t)HDR * 4 + 524288) {
        // ---- tier C: fp32 pyramid in d_out; VALU conv via lagged ws strips ----
        float* pyr = out;
        pyr_init_kernel<<<TOTELEM / 256, 256, 0, stream>>>(f0, f1, f2, f3, pyr);
        for (int i = 0; i < 4; i++)
            for (int j = 0; j < 4; j++)
                fuse_step_kernel<<<65536, 256, 0, stream>>>(pyr, order, wmat, i, j);

        float* stageBase = wsf + HDR;
        size_t availF = ws_size / 4 - HDR;
        const int Hs[4] = {256, 128, 64, 32};
        const int logWs[4] = {8, 7, 6, 5};
        const size_t offs[4] = {0, OFF1, OFF2, OFF3};

        for (int l = 0; l < 4; l++) {
            int H = Hs[l], W = H, HW = H * W, logW = logWs[l];
            size_t lvlF = (size_t)HW * 256;
            float* dst = out + offs[l];

            if (availF >= lvlF) {
                conv_strip_kernel<<<dim3(2, HW / 256), 256, 0, stream>>>(
                    dst, stageBase, H, logW, 0, HW, cw[l], cb[l]);
                copyback_kernel<<<(int)((lvlF / 4 + 255) / 256), 256, 0, stream>>>(
                    dst, stageBase, HW, 0, HW);
            } else {
                size_t bufF = availF / 2;
                int alignR = 256 / W; if (alignR < 1) alignR = 1;
                long rowsFit = (long)(bufF / ((size_t)W * 256));
                int R = (int)((rowsFit < (long)H) ? rowsFit : (long)H);
                R -= R % alignR;
                if (R < alignR) R = alignR;
                float* stg[2] = {stageBase, stageBase + bufF};
                int N = (H + R - 1) / R;
                int prPixBase = 0, prPix = 0;
                for (int i = 0; i < N; i++) {
                    int r0 = i * R;
                    int rows = (H - r0 < R) ? (H - r0) : R;
                    int pixB = r0 * W, sp = rows * W;
                    conv_strip_kernel<<<dim3(2, sp / 256), 256, 0, stream>>>(
                        dst, stg[i & 1], H, logW, pixB, sp, cw[l], cb[l]);
                    if (i > 0)
                        copyback_kernel<<<(((prPix >> 2) << 8) + 255) / 256, 256, 0, stream>>>(
                            dst, stg[(i - 1) & 1], prPix, prPixBase, HW);
                    prPixBase = pixB; prPix = sp;
                }
                copyback_kernel<<<(((prPix >> 2) << 8) + 255) / 256, 256, 0, stream>>>(
                    dst, stg[(N - 1) & 1], prPix, prPixBase, HW);
            }
        }
        return;
    }

    // ---- tier D: fuse in d_out + marker (diagnostic) ----
    {
        float* pyr = out;
        pyr_init_kernel<<<TOTELEM / 256, 256, 0, stream>>>(f0, f1, f2, f3, pyr);
        for (int i = 0; i < 4; i++)
            for (int j = 0; j < 4; j++)
                fuse_step_kernel<<<65536, 256, 0, stream>>>(pyr, order, wmat, i, j);
        size_t mb = ws_size >> 20; if (mb > 100) mb = 100;
        marker_kernel<<<1, 64, 0, stream>>>(out, 32768.f + (float)mb * 128.f);
    }
}

// Round 33
// 513.918 us; speedup vs baseline: 1.0295x; 1.0295x over previous
//
#include <hip/hip_runtime.h>

// ---------------------------------------------------------------------------
// FreeFlowFPN. Inputs fp32, OUTPUT FP32. R32 = 529us (conv 260 dbuf + non-conv
// 269). Non-conv includes 7 fusion launches at 16384 mostly-empty blocks
// (grid sized for worst-case level since order[] is device data) + 4 wconv
// launches. THIS ROUND (one change-set, no math change): fusion kernels are
// grid-stride at 2048 blocks; wconv merged into one launch. Conv = R32 dbuf
// + reg-prefetch verbatim (260us measured).
// ---------------------------------------------------------------------------

#define OFF1 16777216      // 256*256*256
#define OFF2 20971520      // OFF1 + 256*128*128
#define OFF3 22020096      // OFF2 + 256*64*64
#define TOTELEM 22282240   // OFF3 + 256*32*32
#define WTOT 589824        // 256*256*9 weights per level
#define TAU 0.1f
#define HDR 2048           // ws header floats (8KB)

typedef unsigned short u16;
typedef short bf16x8 __attribute__((ext_vector_type(8)));
typedef float f32x4 __attribute__((ext_vector_type(4)));

__device__ __forceinline__ size_t lvl_off(int l) {
    return (l == 0) ? 0 : (l == 1) ? (size_t)OFF1 : (l == 2) ? (size_t)OFF2 : (size_t)OFF3;
}
__device__ __forceinline__ u16 f2bf(float f) {   // RNE
    unsigned u = __float_as_uint(f);
    u += 0x7FFFu + ((u >> 16) & 1u);
    return (u16)(u >> 16);
}

// bilinear sample (fp32), torch align_corners=False (rows then cols)
__device__ __forceinline__ float bilin_sample(const float* __restrict__ srcLvl,
                                              int logHs, int c, int y, int x, int logHt) {
    int Hs = 1 << logHs;
    float scale = (float)Hs / (float)(1 << logHt);
    float sy = fminf(fmaxf(((float)y + 0.5f) * scale - 0.5f, 0.f), (float)(Hs - 1));
    float sx = fminf(fmaxf(((float)x + 0.5f) * scale - 0.5f, 0.f), (float)(Hs - 1));
    int y0 = (int)sy, x0 = (int)sx;
    int y1 = min(y0 + 1, Hs - 1), x1 = min(x0 + 1, Hs - 1);
    float fy = sy - (float)y0, fx = sx - (float)x0;
    const float* sp = srcLvl + ((size_t)c << (2 * logHs));
    float v00 = sp[(size_t)(y0 << logHs) + x0], v01 = sp[(size_t)(y0 << logHs) + x1];
    float v10 = sp[(size_t)(y1 << logHs) + x0], v11 = sp[(size_t)(y1 << logHs) + x1];
    float r0 = v00 * (1.f - fy) + v10 * fy;
    float r1 = v01 * (1.f - fy) + v11 * fy;
    return r0 * (1.f - fx) + r1 * fx;
}

__global__ void marker_kernel(float* __restrict__ out, float v) {
    if (threadIdx.x == 0 && blockIdx.x == 0) out[0] = v;
}

// ---------------- GAP ----------------
__global__ void gap_kernel(const float* __restrict__ f0, const float* __restrict__ f1,
                           const float* __restrict__ f2, const float* __restrict__ f3,
                           float* __restrict__ vecs) {
    int lb = blockIdx.x;
    int level = lb >> 8, c = lb & 255;
    const float* f; int H;
    switch (level) {
        case 0: f = f0; H = 256; break;
        case 1: f = f1; H = 128; break;
        case 2: f = f2; H = 64;  break;
        default: f = f3; H = 32; break;
    }
    int HW = H * H;
    const float* src = f + (size_t)c * HW;
    float s = 0.f;
    for (int i = threadIdx.x; i < HW; i += 256) s += src[i];
    #pragma unroll
    for (int o = 32; o; o >>= 1) s += __shfl_down(s, o);
    __shared__ float red[4];
    int lane = threadIdx.x & 63, wv = threadIdx.x >> 6;
    if (lane == 0) red[wv] = s;
    __syncthreads();
    if (threadIdx.x == 0)
        vecs[level * 256 + c] = (red[0] + red[1] + red[2] + red[3]) / (float)HW;
}

// ---------------- prep ----------------
__global__ void prep_kernel(const float* __restrict__ vecs_g,
                            const float* __restrict__ mlp_w1, const float* __restrict__ mlp_b1,
                            const float* __restrict__ mlp_w2, const float* __restrict__ mlp_b2,
                            const float* __restrict__ qk_w, const float* __restrict__ qk_b,
                            int* __restrict__ order_g, float* __restrict__ wmat_g) {
    __shared__ float vecs[4][256];
    __shared__ float h[4][64];
    __shared__ float scores[4];
    __shared__ float qk[4][512];
    __shared__ float attnS[4][4];
    int t = threadIdx.x;
    for (int i = t; i < 1024; i += 256) vecs[i >> 8][i & 255] = vecs_g[i];
    __syncthreads();
    {
        int l = t >> 6, j = t & 63;
        float s = mlp_b1[j];
        for (int c = 0; c < 256; c++) s += vecs[l][c] * mlp_w1[c * 64 + j];
        h[l][j] = fmaxf(s, 0.f);
    }
    __syncthreads();
    if (t < 4) {
        float s = mlp_b2[0];
        for (int j = 0; j < 64; j++) s += h[t][j] * mlp_w2[j];
        scores[t] = s;
    }
    __syncthreads();
    if (t == 0) {
        bool used[4] = {false, false, false, false};
        for (int r = 0; r < 4; r++) {
            int best = -1; float bv = 0.f;
            for (int l = 0; l < 4; l++)
                if (!used[l] && (best < 0 || scores[l] > bv)) { best = l; bv = scores[l]; }
            used[best] = true;
            order_g[r] = best;
        }
    }
    for (int idx = t; idx < 2048; idx += 256) {
        int l = idx >> 9, col = idx & 511;
        float s = qk_b[col];
        for (int c = 0; c < 256; c++) s += vecs[l][c] * qk_w[c * 512 + col];
        qk[l][col] = s;
    }
    __syncthreads();
    if (t < 16) {
        int i = t >> 2, j = t & 3;
        float s = 0.f;
        for (int c = 0; c < 256; c++) s += qk[i][c] * qk[j][256 + c];
        attnS[i][j] = s * 0.0625f;
    }
    __syncthreads();
    if (t < 4) {
        int i = t;
        float m = -1e30f;
        for (int j = 0; j < 4; j++) if (j != i) m = fmaxf(m, attnS[i][j]);
        float e[4]; float sum = 0.f;
        for (int j = 0; j < 4; j++) {
            e[j] = (j == i) ? 0.f : expf(attnS[i][j] - m);
            sum += e[j];
        }
        for (int j = 0; j < 4; j++) {
            float p = e[j] / sum;
            wmat_g[i * 4 + j] = (p >= TAU) ? p : 0.f;
        }
    }
}

// ---------------- weight convert, ALL levels in one launch ---------------------
__global__ void wconv_all_kernel(const float* __restrict__ w0, const float* __restrict__ w1,
                                 const float* __restrict__ w2, const float* __restrict__ w3,
                                 u16* __restrict__ dst) {
    long long g = ((long long)blockIdx.x * 256 + threadIdx.x) * 8;
    if (g >= (long long)4 * WTOT) return;
    int l = (int)(g / WTOT);
    long long rel = g - (long long)l * WTOT;
    const float* w = (l == 0) ? w0 : (l == 1) ? w1 : (l == 2) ? w2 : w3;
    float4 a = *(const float4*)&w[rel];
    float4 b = *(const float4*)&w[rel + 4];
    uint4 o;
    o.x = ((unsigned)f2bf(a.y) << 16) | f2bf(a.x);
    o.y = ((unsigned)f2bf(a.w) << 16) | f2bf(a.z);
    o.z = ((unsigned)f2bf(b.y) << 16) | f2bf(b.x);
    o.w = ((unsigned)f2bf(b.w) << 16) | f2bf(b.z);
    *(uint4*)&dst[g] = o;
}

// ---------------- G-scheme fusion phase 1, x4 vectorized, grid-stride ----------
__global__ void fuse_build_kernel(const float* __restrict__ f0, const float* __restrict__ f1,
                                  const float* __restrict__ f2, const float* __restrict__ f3,
                                  float* __restrict__ fused, const int* __restrict__ order_g,
                                  const float* __restrict__ wmat, int rank) {
    int t = order_g[rank] & 3;
    int logHt = 8 - t, Ht = 1 << logHt;
    int nVec = (256 << (2 * logHt)) >> 2;
    const float* fr = (t == 0) ? f0 : (t == 1) ? f1 : (t == 2) ? f2 : f3;
    for (int v = blockIdx.x * 256 + threadIdx.x; v < nVec; v += gridDim.x * 256) {
        int e = v << 2;
        int c = e >> (2 * logHt);
        int p = e & ((1 << (2 * logHt)) - 1);
        int y = p >> logHt, x0 = p & (Ht - 1);
        float4 a4 = *(const float4*)&fr[e];
        float av[4] = {a4.x, a4.y, a4.z, a4.w};
        for (int r = 0; r < rank; r++) {
            int s = order_g[r] & 3;
            float w = wmat[s * 4 + t];
            if (w == 0.f) continue;
            const float* src = fused + lvl_off(s);
            #pragma unroll
            for (int j = 0; j < 4; j++)
                av[j] += w * bilin_sample(src, 8 - s, c, y, x0 + j, logHt);
        }
        *(float4*)&fused[lvl_off(t) + e] = make_float4(av[0], av[1], av[2], av[3]);
    }
}

// ---------------- G-scheme fusion phase 2, x4 vectorized, grid-stride ----------
__global__ void fuse_final_kernel(float* __restrict__ fused, const int* __restrict__ order_g,
                                  const float* __restrict__ wmat, int rank) {
    int t = order_g[rank] & 3;
    int logHt = 8 - t, Ht = 1 << logHt;
    int nVec = (256 << (2 * logHt)) >> 2;
    for (int v = blockIdx.x * 256 + threadIdx.x; v < nVec; v += gridDim.x * 256) {
        int e = v << 2;
        int c = e >> (2 * logHt);
        int p = e & ((1 << (2 * logHt)) - 1);
        int y = p >> logHt, x0 = p & (Ht - 1);
        float av[4] = {0.f, 0.f, 0.f, 0.f};
        bool any = false;
        for (int r = rank + 1; r < 4; r++) {
            int s = order_g[r] & 3;
            float w = wmat[s * 4 + t];
            if (w == 0.f) continue;
            any = true;
            const float* src = fused + lvl_off(s);
            #pragma unroll
            for (int j = 0; j < 4; j++)
                av[j] += w * bilin_sample(src, 8 - s, c, y, x0 + j, logHt);
        }
        if (!any) continue;
        size_t idx = lvl_off(t) + e;
        float4 cur = *(const float4*)&fused[idx];
        cur.x += av[0]; cur.y += av[1]; cur.z += av[2]; cur.w += av[3];
        *(float4*)&fused[idx] = cur;
    }
}

// ---------------- MFMA conv: 256cout x 128px, dbuf LDS + reg prefetch ----------
template <bool USE_WB16>
__global__ __launch_bounds__(512, 2) void conv_mfma_kernel(
        const float* __restrict__ pyr, float* __restrict__ outb,
        const float* __restrict__ w0, const float* __restrict__ w1,
        const float* __restrict__ w2, const float* __restrict__ w3,
        const u16* __restrict__ wgtB,
        const float* __restrict__ b0, const float* __restrict__ b1,
        const float* __restrict__ b2, const float* __restrict__ b3) {
    int pt = blockIdx.y;   // L0 [0,512) L1 [512,640) L2 [640,672) L3 [672,680)
    int H, logW, nBase, lvl;
    size_t off;
    const float *wgt, *bias;
    if (pt < 512)      { H = 256; logW = 8; off = 0;    lvl = 0; wgt = w0; bias = b0; nBase = pt << 7; }
    else if (pt < 640) { H = 128; logW = 7; off = OFF1; lvl = 1; wgt = w1; bias = b1; nBase = (pt - 512) << 7; }
    else if (pt < 672) { H = 64;  logW = 6; off = OFF2; lvl = 2; wgt = w2; bias = b2; nBase = (pt - 640) << 7; }
    else               { H = 32;  logW = 5; off = OFF3; lvl = 3; wgt = w3; bias = b3; nBase = (pt - 672) << 7; }
    const int W = H, HW = H * W;
    const float* in = pyr + off;
    const u16* wB = USE_WB16 ? (wgtB + (size_t)lvl * WTOT) : nullptr;
    float* out = outb + off;

    __shared__ short Asm[2][256][40];
    __shared__ short Bsm[2][128][40];
    __shared__ float biasS[256];

    int tid = threadIdx.x;
    int lane = tid & 63, wave = tid >> 6;
    int wr = wave >> 1, wc = wave & 1;     // cout quadrant, px half
    int lm = lane & 15;
    int lkg = lane >> 4;

    if (tid < 256) biasS[tid] = bias[tid];

    int pxB = tid & 127;
    int kkBase = (tid >> 7) << 3;          // 0,8,16,24
    int pxAbs = nBase + pxB;
    int yB = pxAbs >> logW, xB = pxAbs & (W - 1);

    int aRow0 = tid >> 3;
    int aKk4 = (tid & 7) << 2;

    uint2 aReg[4];
    float bReg[8];

    #define LOAD_A(K0)                                                          \
        {                                                                       \
            _Pragma("unroll")                                                   \
            for (int p = 0; p < 4; p++) {                                       \
                int row = aRow0 + p * 64;                                       \
                if (USE_WB16) {                                                 \
                    aReg[p] = *(const uint2*)&wB[(size_t)row * 2304 + (K0) + aKk4]; \
                } else {                                                        \
                    float4 v = *(const float4*)&wgt[(size_t)row * 2304 + (K0) + aKk4]; \
                    aReg[p].x = ((unsigned)f2bf(v.y) << 16) | f2bf(v.x);        \
                    aReg[p].y = ((unsigned)f2bf(v.w) << 16) | f2bf(v.z);        \
                }                                                               \
            }                                                                   \
        }
    #define LOAD_B(K0)                                                          \
        {                                                                       \
            int k = (K0) + kkBase;                                              \
            int ci = k / 9, r = k - ci * 9;                                     \
            _Pragma("unroll")                                                   \
            for (int u = 0; u < 8; u++) {                                       \
                int r3 = (r * 11) >> 5;                                         \
                int dy = r3 - 1, dx = r - r3 * 3 - 1;                           \
                int yy = yB + dy, xx = xB + dx;                                 \
                float v = 0.f;                                                  \
                if (yy >= 0 && yy < H && xx >= 0 && xx < W)                     \
                    v = in[(size_t)ci * HW + yy * W + xx];                      \
                bReg[u] = v;                                                    \
                r++;                                                            \
                if (r == 9) { r = 0; ci++; }                                    \
            }                                                                   \
        }

    f32x4 acc[4][4];
    #pragma unroll
    for (int i = 0; i < 4; i++)
        #pragma unroll
        for (int j = 0; j < 4; j++) acc[i][j] = (f32x4){0.f, 0.f, 0.f, 0.f};

    LOAD_A(0);
    LOAD_B(0);

    int buf = 0;
    for (int k0 = 0; k0 < 2304; k0 += 32) {
        #pragma unroll
        for (int p = 0; p < 4; p++)
            *(uint2*)&Asm[buf][aRow0 + p * 64][aKk4] = aReg[p];
        {
            unsigned bw[4];
            #pragma unroll
            for (int u = 0; u < 8; u++) {
                unsigned b = f2bf(bReg[u]);
                if (u & 1) bw[u >> 1] |= b << 16; else bw[u >> 1] = b;
            }
            *(uint4*)&Bsm[buf][pxB][kkBase] = make_uint4(bw[0], bw[1], bw[2], bw[3]);
        }
        __syncthreads();   // single barrier per K-step (dbuf)

        if (k0 + 32 < 2304) {
            LOAD_A(k0 + 32);
            LOAD_B(k0 + 32);
        }

        bf16x8 af[4], bfr[4];
        #pragma unroll
        for (int fm = 0; fm < 4; fm++)
            af[fm] = *(const bf16x8*)&Asm[buf][wr * 64 + fm * 16 + lm][lkg * 8];
        #pragma unroll
        for (int fc = 0; fc < 4; fc++)
            bfr[fc] = *(const bf16x8*)&Bsm[buf][wc * 64 + fc * 16 + lm][lkg * 8];
        #pragma unroll
        for (int fm = 0; fm < 4; fm++)
            #pragma unroll
            for (int fc = 0; fc < 4; fc++)
                acc[fm][fc] = __builtin_amdgcn_mfma_f32_16x16x32_bf16(
                    af[fm], bfr[fc], acc[fm][fc], 0, 0, 0);
        buf ^= 1;
    }
    #undef LOAD_A
    #undef LOAD_B

    // epilogue (C layout HW-verified: row=(l>>4)*4+reg, col=l&15)
    #pragma unroll
    for (int fm = 0; fm < 4; fm++) {
        #pragma unroll
        for (int reg = 0; reg < 4; reg++) {
            int row = wr * 64 + fm * 16 + lkg * 4 + reg;
            float bi = biasS[row];
            float* op = out + (size_t)row * HW + nBase;
            #pragma unroll
            for (int fc = 0; fc < 4; fc++) {
                int col = wc * 64 + fc * 16 + lm;
                op[col] = fmaxf(acc[fm][fc][reg] + bi, 0.f);
            }
        }
    }
}

// ================= tier-C fallback (R19's proven fp32 VALU path) ===============
__global__ void pyr_init_kernel(const float* __restrict__ f0, const float* __restrict__ f1,
                                const float* __restrict__ f2, const float* __restrict__ f3,
                                float* __restrict__ pyr) {
    long long e = (long long)blockIdx.x * 256 + threadIdx.x;
    if (e >= TOTELEM) return;
    float v;
    if (e < OFF1)      v = f0[e];
    else if (e < OFF2) v = f1[e - OFF1];
    else if (e < OFF3) v = f2[e - OFF2];
    else               v = f3[e - OFF3];
    pyr[e] = v;
}

__global__ void fuse_step_kernel(float* __restrict__ pyr, const int* __restrict__ order_g,
                                 const float* __restrict__ wmat, int oi, int oj) {
    int a = order_g[oi] & 3, b = order_g[oj] & 3;
    if (a == b) return;
    float w = wmat[a * 4 + b];
    if (w == 0.f) return;
    int logHb = 8 - b, Hb = 1 << logHb;
    int nElem = 256 << (2 * logHb);
    int e = blockIdx.x * 256 + threadIdx.x;
    if (e >= nElem) return;
    int c = e >> (2 * logHb);
    int p = e & ((1 << (2 * logHb)) - 1);
    int y = p >> logHb, x = p & (Hb - 1);
    float val = bilin_sample(pyr + lvl_off(a), 8 - a, c, y, x, logHb);
    pyr[lvl_off(b) + e] += w * val;
}

__global__ __launch_bounds__(256, 2) void conv_strip_kernel(
        const float* __restrict__ in, float* __restrict__ stage,
        int H, int logW, int pixBase, int stripPix,
        const float* __restrict__ wgt, const float* __restrict__ bias) {
    const int W = H, HW = H * W;
    int nAbs = pixBase + blockIdx.y * 256;

    __shared__ float As[8][132];
    __shared__ float Bs[8][256];
    int tid = threadIdx.x;
    int tm = tid >> 4, tn = tid & 15;
    int coutBase = blockIdx.x * 128;
    int pixS = nAbs + tid;
    int yS = pixS >> logW, xS = pixS & (W - 1);

    float acc[8][16];
    #pragma unroll
    for (int i = 0; i < 8; i++)
        #pragma unroll
        for (int j = 0; j < 16; j++) acc[i][j] = 0.f;

    for (int k0 = 0; k0 < 2304; k0 += 8) {
        #pragma unroll
        for (int u = 0; u < 4; u++) {
            int co = (tid >> 3) + u * 32;
            int kk = tid & 7;
            As[kk][co] = wgt[(size_t)(coutBase + co) * 2304 + k0 + kk];
        }
        #pragma unroll
        for (int u = 0; u < 8; u++) {
            int k = k0 + u;
            int ci = k / 9, r = k - ci * 9;
            int rr = r / 3;
            int dy = rr - 1, dx = r - rr * 3 - 1;
            int yy = yS + dy, xx = xS + dx;
            float v = 0.f;
            if (yy >= 0 && yy < H && xx >= 0 && xx < W)
                v = in[(size_t)ci * HW + yy * W + xx];
            Bs[u][tid] = v;
        }
        __syncthreads();
        #pragma unroll
        for (int kk = 0; kk < 8; kk++) {
            float a[8], b[16];
            *(float4*)&a[0] = *(const float4*)&As[kk][tm * 8];
            *(float4*)&a[4] = *(const float4*)&As[kk][tm * 8 + 4];
            *(float4*)&b[0]  = *(const float4*)&Bs[kk][tn * 4];
            *(float4*)&b[4]  = *(const float4*)&Bs[kk][64 + tn * 4];
            *(float4*)&b[8]  = *(const float4*)&Bs[kk][128 + tn * 4];
            *(float4*)&b[12] = *(const float4*)&Bs[kk][192 + tn * 4];
            #pragma unroll
            for (int i = 0; i < 8; i++)
                #pragma unroll
                for (int j = 0; j < 16; j++)
                    acc[i][j] = fmaf(a[i], b[j], acc[i][j]);
        }
        __syncthreads();
    }
    int nLoc = nAbs - pixBase;
    #pragma unroll
    for (int i = 0; i < 8; i++) {
        int co = coutBase + tm * 8 + i;
        float bi = bias[co];
        float* op = stage + (size_t)co * stripPix + nLoc;
        #pragma unroll
        for (int ch = 0; ch < 4; ch++) {
            float4 o;
            o.x = fmaxf(acc[i][ch * 4 + 0] + bi, 0.f);
            o.y = fmaxf(acc[i][ch * 4 + 1] + bi, 0.f);
            o.z = fmaxf(acc[i][ch * 4 + 2] + bi, 0.f);
            o.w = fmaxf(acc[i][ch * 4 + 3] + bi, 0.f);
            *(float4*)(op + ch * 64 + tn * 4) = o;
        }
    }
}

__global__ void copyback_kernel(float* __restrict__ dst, const float* __restrict__ stage,
                                int stripPix, int pixBase, int HW) {
    int gid = blockIdx.x * 256 + threadIdx.x;
    int q = stripPix >> 2;
    int total = q << 8;
    if (gid >= total) return;
    int c = gid / q, rem = gid - c * q;
    float4 v = ((const float4*)stage)[(size_t)c * q + rem];
    ((float4*)(dst + (size_t)c * HW + pixBase))[rem] = v;
}

extern "C" void kernel_launch(void* const* d_in, const int* in_sizes, int n_in,
                              void* d_out, int out_size, void* d_ws, size_t ws_size,
                              hipStream_t stream) {
    const float* f0 = (const float*)d_in[0];
    const float* f1 = (const float*)d_in[1];
    const float* f2 = (const float*)d_in[2];
    const float* f3 = (const float*)d_in[3];
    float* out = (float*)d_out;

    int wi[4], bx[4];
    if (n_in >= 18 && in_sizes[11] == 256) {
        for (int l = 0; l < 4; l++) { wi[l] = 10 + 2 * l; bx[l] = 11 + 2 * l; }
    } else {
        for (int l = 0; l < 4; l++) { wi[l] = 10 + l; bx[l] = 14 + l; }
    }
    const float* cw[4] = {(const float*)d_in[wi[0]], (const float*)d_in[wi[1]],
                          (const float*)d_in[wi[2]], (const float*)d_in[wi[3]]};
    const float* cb[4] = {(const float*)d_in[bx[0]], (const float*)d_in[bx[1]],
                          (const float*)d_in[bx[2]], (const float*)d_in[bx[3]]};

    if (ws_size < (size_t)HDR * 4) {
        size_t kb = ws_size / 1024; if (kb > 7) kb = 7;
        marker_kernel<<<1, 64, 0, stream>>>(out, 49152.f + (float)kb * 128.f);
        return;
    }

    float* wsf = (float*)d_ws;
    float* vecs = wsf;
    int* order = (int*)(wsf + 1024);
    float* wmat = wsf + 1040;

    gap_kernel<<<1024, 256, 0, stream>>>(f0, f1, f2, f3, vecs);
    prep_kernel<<<1, 256, 0, stream>>>(vecs,
        (const float*)d_in[4], (const float*)d_in[5], (const float*)d_in[6],
        (const float*)d_in[7], (const float*)d_in[8], (const float*)d_in[9],
        order, wmat);

    size_t needA0 = (size_t)HDR * 4 + (size_t)TOTELEM * 4;
    size_t needA1 = needA0 + (size_t)4 * WTOT * 2;   // + bf16 weights (4.7MB)

    if (ws_size >= needA0) {
        // ---- tier A: fp32 G-scheme fusion (grid-stride) -> MFMA conv -> d_out
        float* pyr = wsf + HDR;
        for (int k = 0; k < 4; k++)
            fuse_build_kernel<<<2048, 256, 0, stream>>>(f0, f1, f2, f3,
                                                        pyr, order, wmat, k);
        for (int k = 0; k < 3; k++)
            fuse_final_kernel<<<2048, 256, 0, stream>>>(pyr, order, wmat, k);

        if (ws_size >= needA1) {
            u16* wgtB = (u16*)(pyr + (size_t)TOTELEM);
            wconv_all_kernel<<<(4 * WTOT / 8 + 255) / 256, 256, 0, stream>>>(
                cw[0], cw[1], cw[2], cw[3], wgtB);
            conv_mfma_kernel<true><<<dim3(1, 680), 512, 0, stream>>>(
                pyr, out, cw[0], cw[1], cw[2], cw[3], wgtB,
                cb[0], cb[1], cb[2], cb[3]);
        } else {
            conv_mfma_kernel<false><<<dim3(1, 680), 512, 0, stream>>>(
                pyr, out, cw[0], cw[1], cw[2], cw[3], (const u16*)nullptr,
                cb[0], cb[1], cb[2], cb[3]);
        }
        return;
    }

    if (ws_size >= (size_t)HDR * 4 + 524288) {
        // ---- tier C: fp32 pyramid in d_out; VALU conv via lagged ws strips ----
        float* pyr = out;
        pyr_init_kernel<<<TOTELEM / 256, 256, 0, stream>>>(f0, f1, f2, f3, pyr);
        for (int i = 0; i < 4; i++)
            for (int j = 0; j < 4; j++)
                fuse_step_kernel<<<65536, 256, 0, stream>>>(pyr, order, wmat, i, j);

        float* stageBase = wsf + HDR;
        size_t availF = ws_size / 4 - HDR;
        const int Hs[4] = {256, 128, 64, 32};
        const int logWs[4] = {8, 7, 6, 5};
        const size_t offs[4] = {0, OFF1, OFF2, OFF3};

        for (int l = 0; l < 4; l++) {
            int H = Hs[l], W = H, HW = H * W, logW = logWs[l];
            size_t lvlF = (size_t)HW * 256;
            float* dst = out + offs[l];

            if (availF >= lvlF) {
                conv_strip_kernel<<<dim3(2, HW / 256), 256, 0, stream>>>(
                    dst, stageBase, H, logW, 0, HW, cw[l], cb[l]);
                copyback_kernel<<<(int)((lvlF / 4 + 255) / 256), 256, 0, stream>>>(
                    dst, stageBase, HW, 0, HW);
            } else {
                size_t bufF = availF / 2;
                int alignR = 256 / W; if (alignR < 1) alignR = 1;
                long rowsFit = (long)(bufF / ((size_t)W * 256));
                int R = (int)((rowsFit < (long)H) ? rowsFit : (long)H);
                R -= R % alignR;
                if (R < alignR) R = alignR;
                float* stg[2] = {stageBase, stageBase + bufF};
                int N = (H + R - 1) / R;
                int prPixBase = 0, prPix = 0;
                for (int i = 0; i < N; i++) {
                    int r0 = i * R;
                    int rows = (H - r0 < R) ? (H - r0) : R;
                    int pixB = r0 * W, sp = rows * W;
                    conv_strip_kernel<<<dim3(2, sp / 256), 256, 0, stream>>>(
                        dst, stg[i & 1], H, logW, pixB, sp, cw[l], cb[l]);
                    if (i > 0)
                        copyback_kernel<<<(((prPix >> 2) << 8) + 255) / 256, 256, 0, stream>>>(
                            dst, stg[(i - 1) & 1], prPix, prPixBase, HW);
                    prPixBase = pixB; prPix = sp;
                }
                copyback_kernel<<<(((prPix >> 2) << 8) + 255) / 256, 256, 0, stream>>>(
                    dst, stg[(N - 1) & 1], prPix, prPixBase, HW);
            }
        }
        return;
    }

    // ---- tier D: fuse in d_out + marker (diagnostic) ----
    {
        float* pyr = out;
        pyr_init_kernel<<<TOTELEM / 256, 256, 0, stream>>>(f0, f1, f2, f3, pyr);
        for (int i = 0; i < 4; i++)
            for (int j = 0; j < 4; j++)
                fuse_step_kernel<<<65536, 256, 0, stream>>>(pyr, order, wmat, i, j);
        size_t mb = ws_size >> 20; if (mb > 100) mb = 100;
        marker_kernel<<<1, 64, 0, stream>>>(out, 32768.f + (float)mb * 128.f);
    }
}

// Round 34
// 501.270 us; speedup vs baseline: 1.0554x; 1.0252x over previous
//
#include <hip/hip_runtime.h>

// ---------------------------------------------------------------------------
// FreeFlowFPN. Inputs fp32, OUTPUT FP32. R33 = 514us (conv 259 + non-conv 255).
// THIS ROUND (one change): prep_kernel runs with 1024 threads (was 256) —
// the qk projection (524KB reads, 524K MACs) is single-block/single-CU and
// latency-bound at 4 waves; 16 waves quadruple outstanding loads.
// Everything else byte-identical to R33 (conv dbuf+prefetch, grid-stride
// fusion, merged wconv).
// ---------------------------------------------------------------------------

#define OFF1 16777216      // 256*256*256
#define OFF2 20971520      // OFF1 + 256*128*128
#define OFF3 22020096      // OFF2 + 256*64*64
#define TOTELEM 22282240   // OFF3 + 256*32*32
#define WTOT 589824        // 256*256*9 weights per level
#define TAU 0.1f
#define HDR 2048           // ws header floats (8KB)

typedef unsigned short u16;
typedef short bf16x8 __attribute__((ext_vector_type(8)));
typedef float f32x4 __attribute__((ext_vector_type(4)));

__device__ __forceinline__ size_t lvl_off(int l) {
    return (l == 0) ? 0 : (l == 1) ? (size_t)OFF1 : (l == 2) ? (size_t)OFF2 : (size_t)OFF3;
}
__device__ __forceinline__ u16 f2bf(float f) {   // RNE
    unsigned u = __float_as_uint(f);
    u += 0x7FFFu + ((u >> 16) & 1u);
    return (u16)(u >> 16);
}

// bilinear sample (fp32), torch align_corners=False (rows then cols)
__device__ __forceinline__ float bilin_sample(const float* __restrict__ srcLvl,
                                              int logHs, int c, int y, int x, int logHt) {
    int Hs = 1 << logHs;
    float scale = (float)Hs / (float)(1 << logHt);
    float sy = fminf(fmaxf(((float)y + 0.5f) * scale - 0.5f, 0.f), (float)(Hs - 1));
    float sx = fminf(fmaxf(((float)x + 0.5f) * scale - 0.5f, 0.f), (float)(Hs - 1));
    int y0 = (int)sy, x0 = (int)sx;
    int y1 = min(y0 + 1, Hs - 1), x1 = min(x0 + 1, Hs - 1);
    float fy = sy - (float)y0, fx = sx - (float)x0;
    const float* sp = srcLvl + ((size_t)c << (2 * logHs));
    float v00 = sp[(size_t)(y0 << logHs) + x0], v01 = sp[(size_t)(y0 << logHs) + x1];
    float v10 = sp[(size_t)(y1 << logHs) + x0], v11 = sp[(size_t)(y1 << logHs) + x1];
    float r0 = v00 * (1.f - fy) + v10 * fy;
    float r1 = v01 * (1.f - fy) + v11 * fy;
    return r0 * (1.f - fx) + r1 * fx;
}

__global__ void marker_kernel(float* __restrict__ out, float v) {
    if (threadIdx.x == 0 && blockIdx.x == 0) out[0] = v;
}

// ---------------- GAP ----------------
__global__ void gap_kernel(const float* __restrict__ f0, const float* __restrict__ f1,
                           const float* __restrict__ f2, const float* __restrict__ f3,
                           float* __restrict__ vecs) {
    int lb = blockIdx.x;
    int level = lb >> 8, c = lb & 255;
    const float* f; int H;
    switch (level) {
        case 0: f = f0; H = 256; break;
        case 1: f = f1; H = 128; break;
        case 2: f = f2; H = 64;  break;
        default: f = f3; H = 32; break;
    }
    int HW = H * H;
    const float* src = f + (size_t)c * HW;
    float s = 0.f;
    for (int i = threadIdx.x; i < HW; i += 256) s += src[i];
    #pragma unroll
    for (int o = 32; o; o >>= 1) s += __shfl_down(s, o);
    __shared__ float red[4];
    int lane = threadIdx.x & 63, wv = threadIdx.x >> 6;
    if (lane == 0) red[wv] = s;
    __syncthreads();
    if (threadIdx.x == 0)
        vecs[level * 256 + c] = (red[0] + red[1] + red[2] + red[3]) / (float)HW;
}

// ---------------- prep (1024 threads: 16 waves for the qk projection) ----------
__global__ __launch_bounds__(1024) void prep_kernel(
        const float* __restrict__ vecs_g,
        const float* __restrict__ mlp_w1, const float* __restrict__ mlp_b1,
        const float* __restrict__ mlp_w2, const float* __restrict__ mlp_b2,
        const float* __restrict__ qk_w, const float* __restrict__ qk_b,
        int* __restrict__ order_g, float* __restrict__ wmat_g) {
    __shared__ float vecs[4][256];
    __shared__ float h[4][64];
    __shared__ float scores[4];
    __shared__ float qk[4][512];
    __shared__ float attnS[4][4];
    int t = threadIdx.x;
    if (t < 1024) vecs[t >> 8][t & 255] = vecs_g[t];
    __syncthreads();
    if (t < 256) {
        int l = t >> 6, j = t & 63;
        float s = mlp_b1[j];
        for (int c = 0; c < 256; c++) s += vecs[l][c] * mlp_w1[c * 64 + j];
        h[l][j] = fmaxf(s, 0.f);
    }
    __syncthreads();
    if (t < 4) {
        float s = mlp_b2[0];
        for (int j = 0; j < 64; j++) s += h[t][j] * mlp_w2[j];
        scores[t] = s;
    }
    __syncthreads();
    if (t == 0) {
        bool used[4] = {false, false, false, false};
        for (int r = 0; r < 4; r++) {
            int best = -1; float bv = 0.f;
            for (int l = 0; l < 4; l++)
                if (!used[l] && (best < 0 || scores[l] > bv)) { best = l; bv = scores[l]; }
            used[best] = true;
            order_g[r] = best;
        }
    }
    // qk projection: 2048 items over 1024 threads (2 iterations)
    for (int idx = t; idx < 2048; idx += 1024) {
        int l = idx >> 9, col = idx & 511;
        float s = qk_b[col];
        for (int c = 0; c < 256; c++) s += vecs[l][c] * qk_w[c * 512 + col];
        qk[l][col] = s;
    }
    __syncthreads();
    if (t < 16) {
        int i = t >> 2, j = t & 3;
        float s = 0.f;
        for (int c = 0; c < 256; c++) s += qk[i][c] * qk[j][256 + c];
        attnS[i][j] = s * 0.0625f;
    }
    __syncthreads();
    if (t < 4) {
        int i = t;
        float m = -1e30f;
        for (int j = 0; j < 4; j++) if (j != i) m = fmaxf(m, attnS[i][j]);
        float e[4]; float sum = 0.f;
        for (int j = 0; j < 4; j++) {
            e[j] = (j == i) ? 0.f : expf(attnS[i][j] - m);
            sum += e[j];
        }
        for (int j = 0; j < 4; j++) {
            float p = e[j] / sum;
            wmat_g[i * 4 + j] = (p >= TAU) ? p : 0.f;
        }
    }
}

// ---------------- weight convert, ALL levels in one launch ---------------------
__global__ void wconv_all_kernel(const float* __restrict__ w0, const float* __restrict__ w1,
                                 const float* __restrict__ w2, const float* __restrict__ w3,
                                 u16* __restrict__ dst) {
    long long g = ((long long)blockIdx.x * 256 + threadIdx.x) * 8;
    if (g >= (long long)4 * WTOT) return;
    int l = (int)(g / WTOT);
    long long rel = g - (long long)l * WTOT;
    const float* w = (l == 0) ? w0 : (l == 1) ? w1 : (l == 2) ? w2 : w3;
    float4 a = *(const float4*)&w[rel];
    float4 b = *(const float4*)&w[rel + 4];
    uint4 o;
    o.x = ((unsigned)f2bf(a.y) << 16) | f2bf(a.x);
    o.y = ((unsigned)f2bf(a.w) << 16) | f2bf(a.z);
    o.z = ((unsigned)f2bf(b.y) << 16) | f2bf(b.x);
    o.w = ((unsigned)f2bf(b.w) << 16) | f2bf(b.z);
    *(uint4*)&dst[g] = o;
}

// ---------------- G-scheme fusion phase 1, x4 vectorized, grid-stride ----------
__global__ void fuse_build_kernel(const float* __restrict__ f0, const float* __restrict__ f1,
                                  const float* __restrict__ f2, const float* __restrict__ f3,
                                  float* __restrict__ fused, const int* __restrict__ order_g,
                                  const float* __restrict__ wmat, int rank) {
    int t = order_g[rank] & 3;
    int logHt = 8 - t, Ht = 1 << logHt;
    int nVec = (256 << (2 * logHt)) >> 2;
    const float* fr = (t == 0) ? f0 : (t == 1) ? f1 : (t == 2) ? f2 : f3;
    for (int v = blockIdx.x * 256 + threadIdx.x; v < nVec; v += gridDim.x * 256) {
        int e = v << 2;
        int c = e >> (2 * logHt);
        int p = e & ((1 << (2 * logHt)) - 1);
        int y = p >> logHt, x0 = p & (Ht - 1);
        float4 a4 = *(const float4*)&fr[e];
        float av[4] = {a4.x, a4.y, a4.z, a4.w};
        for (int r = 0; r < rank; r++) {
            int s = order_g[r] & 3;
            float w = wmat[s * 4 + t];
            if (w == 0.f) continue;
            const float* src = fused + lvl_off(s);
            #pragma unroll
            for (int j = 0; j < 4; j++)
                av[j] += w * bilin_sample(src, 8 - s, c, y, x0 + j, logHt);
        }
        *(float4*)&fused[lvl_off(t) + e] = make_float4(av[0], av[1], av[2], av[3]);
    }
}

// ---------------- G-scheme fusion phase 2, x4 vectorized, grid-stride ----------
__global__ void fuse_final_kernel(float* __restrict__ fused, const int* __restrict__ order_g,
                                  const float* __restrict__ wmat, int rank) {
    int t = order_g[rank] & 3;
    int logHt = 8 - t, Ht = 1 << logHt;
    int nVec = (256 << (2 * logHt)) >> 2;
    for (int v = blockIdx.x * 256 + threadIdx.x; v < nVec; v += gridDim.x * 256) {
        int e = v << 2;
        int c = e >> (2 * logHt);
        int p = e & ((1 << (2 * logHt)) - 1);
        int y = p >> logHt, x0 = p & (Ht - 1);
        float av[4] = {0.f, 0.f, 0.f, 0.f};
        bool any = false;
        for (int r = rank + 1; r < 4; r++) {
            int s = order_g[r] & 3;
            float w = wmat[s * 4 + t];
            if (w == 0.f) continue;
            any = true;
            const float* src = fused + lvl_off(s);
            #pragma unroll
            for (int j = 0; j < 4; j++)
                av[j] += w * bilin_sample(src, 8 - s, c, y, x0 + j, logHt);
        }
        if (!any) continue;
        size_t idx = lvl_off(t) + e;
        float4 cur = *(const float4*)&fused[idx];
        cur.x += av[0]; cur.y += av[1]; cur.z += av[2]; cur.w += av[3];
        *(float4*)&fused[idx] = cur;
    }
}

// ---------------- MFMA conv: 256cout x 128px, dbuf LDS + reg prefetch ----------
template <bool USE_WB16>
__global__ __launch_bounds__(512, 2) void conv_mfma_kernel(
        const float* __restrict__ pyr, float* __restrict__ outb,
        const float* __restrict__ w0, const float* __restrict__ w1,
        const float* __restrict__ w2, const float* __restrict__ w3,
        const u16* __restrict__ wgtB,
        const float* __restrict__ b0, const float* __restrict__ b1,
        const float* __restrict__ b2, const float* __restrict__ b3) {
    int pt = blockIdx.y;   // L0 [0,512) L1 [512,640) L2 [640,672) L3 [672,680)
    int H, logW, nBase, lvl;
    size_t off;
    const float *wgt, *bias;
    if (pt < 512)      { H = 256; logW = 8; off = 0;    lvl = 0; wgt = w0; bias = b0; nBase = pt << 7; }
    else if (pt < 640) { H = 128; logW = 7; off = OFF1; lvl = 1; wgt = w1; bias = b1; nBase = (pt - 512) << 7; }
    else if (pt < 672) { H = 64;  logW = 6; off = OFF2; lvl = 2; wgt = w2; bias = b2; nBase = (pt - 640) << 7; }
    else               { H = 32;  logW = 5; off = OFF3; lvl = 3; wgt = w3; bias = b3; nBase = (pt - 672) << 7; }
    const int W = H, HW = H * W;
    const float* in = pyr + off;
    const u16* wB = USE_WB16 ? (wgtB + (size_t)lvl * WTOT) : nullptr;
    float* out = outb + off;

    __shared__ short Asm[2][256][40];
    __shared__ short Bsm[2][128][40];
    __shared__ float biasS[256];

    int tid = threadIdx.x;
    int lane = tid & 63, wave = tid >> 6;
    int wr = wave >> 1, wc = wave & 1;     // cout quadrant, px half
    int lm = lane & 15;
    int lkg = lane >> 4;

    if (tid < 256) biasS[tid] = bias[tid];

    int pxB = tid & 127;
    int kkBase = (tid >> 7) << 3;          // 0,8,16,24
    int pxAbs = nBase + pxB;
    int yB = pxAbs >> logW, xB = pxAbs & (W - 1);

    int aRow0 = tid >> 3;
    int aKk4 = (tid & 7) << 2;

    uint2 aReg[4];
    float bReg[8];

    #define LOAD_A(K0)                                                          \
        {                                                                       \
            _Pragma("unroll")                                                   \
            for (int p = 0; p < 4; p++) {                                       \
                int row = aRow0 + p * 64;                                       \
                if (USE_WB16) {                                                 \
                    aReg[p] = *(const uint2*)&wB[(size_t)row * 2304 + (K0) + aKk4]; \
                } else {                                                        \
                    float4 v = *(const float4*)&wgt[(size_t)row * 2304 + (K0) + aKk4]; \
                    aReg[p].x = ((unsigned)f2bf(v.y) << 16) | f2bf(v.x);        \
                    aReg[p].y = ((unsigned)f2bf(v.w) << 16) | f2bf(v.z);        \
                }                                                               \
            }                                                                   \
        }
    #define LOAD_B(K0)                                                          \
        {                                                                       \
            int k = (K0) + kkBase;                                              \
            int ci = k / 9, r = k - ci * 9;                                     \
            _Pragma("unroll")                                                   \
            for (int u = 0; u < 8; u++) {                                       \
                int r3 = (r * 11) >> 5;                                         \
                int dy = r3 - 1, dx = r - r3 * 3 - 1;                           \
                int yy = yB + dy, xx = xB + dx;                                 \
                float v = 0.f;                                                  \
                if (yy >= 0 && yy < H && xx >= 0 && xx < W)                     \
                    v = in[(size_t)ci * HW + yy * W + xx];                      \
                bReg[u] = v;                                                    \
                r++;                                                            \
                if (r == 9) { r = 0; ci++; }                                    \
            }                                                                   \
        }

    f32x4 acc[4][4];
    #pragma unroll
    for (int i = 0; i < 4; i++)
        #pragma unroll
        for (int j = 0; j < 4; j++) acc[i][j] = (f32x4){0.f, 0.f, 0.f, 0.f};

    LOAD_A(0);
    LOAD_B(0);

    int buf = 0;
    for (int k0 = 0; k0 < 2304; k0 += 32) {
        #pragma unroll
        for (int p = 0; p < 4; p++)
            *(uint2*)&Asm[buf][aRow0 + p * 64][aKk4] = aReg[p];
        {
            unsigned bw[4];
            #pragma unroll
            for (int u = 0; u < 8; u++) {
                unsigned b = f2bf(bReg[u]);
                if (u & 1) bw[u >> 1] |= b << 16; else bw[u >> 1] = b;
            }
            *(uint4*)&Bsm[buf][pxB][kkBase] = make_uint4(bw[0], bw[1], bw[2], bw[3]);
        }
        __syncthreads();   // single barrier per K-step (dbuf)

        if (k0 + 32 < 2304) {
            LOAD_A(k0 + 32);
            LOAD_B(k0 + 32);
        }

        bf16x8 af[4], bfr[4];
        #pragma unroll
        for (int fm = 0; fm < 4; fm++)
            af[fm] = *(const bf16x8*)&Asm[buf][wr * 64 + fm * 16 + lm][lkg * 8];
        #pragma unroll
        for (int fc = 0; fc < 4; fc++)
            bfr[fc] = *(const bf16x8*)&Bsm[buf][wc * 64 + fc * 16 + lm][lkg * 8];
        #pragma unroll
        for (int fm = 0; fm < 4; fm++)
            #pragma unroll
            for (int fc = 0; fc < 4; fc++)
                acc[fm][fc] = __builtin_amdgcn_mfma_f32_16x16x32_bf16(
                    af[fm], bfr[fc], acc[fm][fc], 0, 0, 0);
        buf ^= 1;
    }
    #undef LOAD_A
    #undef LOAD_B

    // epilogue (C layout HW-verified: row=(l>>4)*4+reg, col=l&15)
    #pragma unroll
    for (int fm = 0; fm < 4; fm++) {
        #pragma unroll
        for (int reg = 0; reg < 4; reg++) {
            int row = wr * 64 + fm * 16 + lkg * 4 + reg;
            float bi = biasS[row];
            float* op = out + (size_t)row * HW + nBase;
            #pragma unroll
            for (int fc = 0; fc < 4; fc++) {
                int col = wc * 64 + fc * 16 + lm;
                op[col] = fmaxf(acc[fm][fc][reg] + bi, 0.f);
            }
        }
    }
}

// ================= tier-C fallback (R19's proven fp32 VALU path) ===============
__global__ void pyr_init_kernel(const float* __restrict__ f0, const float* __restrict__ f1,
                                const float* __restrict__ f2, const float* __restrict__ f3,
                                float* __restrict__ pyr) {
    long long e = (long long)blockIdx.x * 256 + threadIdx.x;
    if (e >= TOTELEM) return;
    float v;
    if (e < OFF1)      v = f0[e];
    else if (e < OFF2) v = f1[e - OFF1];
    else if (e < OFF3) v = f2[e - OFF2];
    else               v = f3[e - OFF3];
    pyr[e] = v;
}

__global__ void fuse_step_kernel(float* __restrict__ pyr, const int* __restrict__ order_g,
                                 const float* __restrict__ wmat, int oi, int oj) {
    int a = order_g[oi] & 3, b = order_g[oj] & 3;
    if (a == b) return;
    float w = wmat[a * 4 + b];
    if (w == 0.f) return;
    int logHb = 8 - b, Hb = 1 << logHb;
    int nElem = 256 << (2 * logHb);
    int e = blockIdx.x * 256 + threadIdx.x;
    if (e >= nElem) return;
    int c = e >> (2 * logHb);
    int p = e & ((1 << (2 * logHb)) - 1);
    int y = p >> logHb, x = p & (Hb - 1);
    float val = bilin_sample(pyr + lvl_off(a), 8 - a, c, y, x, logHb);
    pyr[lvl_off(b) + e] += w * val;
}

__global__ __launch_bounds__(256, 2) void conv_strip_kernel(
        const float* __restrict__ in, float* __restrict__ stage,
        int H, int logW, int pixBase, int stripPix,
        const float* __restrict__ wgt, const float* __restrict__ bias) {
    const int W = H, HW = H * W;
    int nAbs = pixBase + blockIdx.y * 256;

    __shared__ float As[8][132];
    __shared__ float Bs[8][256];
    int tid = threadIdx.x;
    int tm = tid >> 4, tn = tid & 15;
    int coutBase = blockIdx.x * 128;
    int pixS = nAbs + tid;
    int yS = pixS >> logW, xS = pixS & (W - 1);

    float acc[8][16];
    #pragma unroll
    for (int i = 0; i < 8; i++)
        #pragma unroll
        for (int j = 0; j < 16; j++) acc[i][j] = 0.f;

    for (int k0 = 0; k0 < 2304; k0 += 8) {
        #pragma unroll
        for (int u = 0; u < 4; u++) {
            int co = (tid >> 3) + u * 32;
            int kk = tid & 7;
            As[kk][co] = wgt[(size_t)(coutBase + co) * 2304 + k0 + kk];
        }
        #pragma unroll
        for (int u = 0; u < 8; u++) {
            int k = k0 + u;
            int ci = k / 9, r = k - ci * 9;
            int rr = r / 3;
            int dy = rr - 1, dx = r - rr * 3 - 1;
            int yy = yS + dy, xx = xS + dx;
            float v = 0.f;
            if (yy >= 0 && yy < H && xx >= 0 && xx < W)
                v = in[(size_t)ci * HW + yy * W + xx];
            Bs[u][tid] = v;
        }
        __syncthreads();
        #pragma unroll
        for (int kk = 0; kk < 8; kk++) {
            float a[8], b[16];
            *(float4*)&a[0] = *(const float4*)&As[kk][tm * 8];
            *(float4*)&a[4] = *(const float4*)&As[kk][tm * 8 + 4];
            *(float4*)&b[0]  = *(const float4*)&Bs[kk][tn * 4];
            *(float4*)&b[4]  = *(const float4*)&Bs[kk][64 + tn * 4];
            *(float4*)&b[8]  = *(const float4*)&Bs[kk][128 + tn * 4];
            *(float4*)&b[12] = *(const float4*)&Bs[kk][192 + tn * 4];
            #pragma unroll
            for (int i = 0; i < 8; i++)
                #pragma unroll
                for (int j = 0; j < 16; j++)
                    acc[i][j] = fmaf(a[i], b[j], acc[i][j]);
        }
        __syncthreads();
    }
    int nLoc = nAbs - pixBase;
    #pragma unroll
    for (int i = 0; i < 8; i++) {
        int co = coutBase + tm * 8 + i;
        float bi = bias[co];
        float* op = stage + (size_t)co * stripPix + nLoc;
        #pragma unroll
        for (int ch = 0; ch < 4; ch++) {
            float4 o;
            o.x = fmaxf(acc[i][ch * 4 + 0] + bi, 0.f);
            o.y = fmaxf(acc[i][ch * 4 + 1] + bi, 0.f);
            o.z = fmaxf(acc[i][ch * 4 + 2] + bi, 0.f);
            o.w = fmaxf(acc[i][ch * 4 + 3] + bi, 0.f);
            *(float4*)(op + ch * 64 + tn * 4) = o;
        }
    }
}

__global__ void copyback_kernel(float* __restrict__ dst, const float* __restrict__ stage,
                                int stripPix, int pixBase, int HW) {
    int gid = blockIdx.x * 256 + threadIdx.x;
    int q = stripPix >> 2;
    int total = q << 8;
    if (gid >= total) return;
    int c = gid / q, rem = gid - c * q;
    float4 v = ((const float4*)stage)[(size_t)c * q + rem];
    ((float4*)(dst + (size_t)c * HW + pixBase))[rem] = v;
}

extern "C" void kernel_launch(void* const* d_in, const int* in_sizes, int n_in,
                              void* d_out, int out_size, void* d_ws, size_t ws_size,
                              hipStream_t stream) {
    const float* f0 = (const float*)d_in[0];
    const float* f1 = (const float*)d_in[1];
    const float* f2 = (const float*)d_in[2];
    const float* f3 = (const float*)d_in[3];
    float* out = (float*)d_out;

    int wi[4], bx[4];
    if (n_in >= 18 && in_sizes[11] == 256) {
        for (int l = 0; l < 4; l++) { wi[l] = 10 + 2 * l; bx[l] = 11 + 2 * l; }
    } else {
        for (int l = 0; l < 4; l++) { wi[l] = 10 + l; bx[l] = 14 + l; }
    }
    const float* cw[4] = {(const float*)d_in[wi[0]], (const float*)d_in[wi[1]],
                          (const float*)d_in[wi[2]], (const float*)d_in[wi[3]]};
    const float* cb[4] = {(const float*)d_in[bx[0]], (const float*)d_in[bx[1]],
                          (const float*)d_in[bx[2]], (const float*)d_in[bx[3]]};

    if (ws_size < (size_t)HDR * 4) {
        size_t kb = ws_size / 1024; if (kb > 7) kb = 7;
        marker_kernel<<<1, 64, 0, stream>>>(out, 49152.f + (float)kb * 128.f);
        return;
    }

    float* wsf = (float*)d_ws;
    float* vecs = wsf;
    int* order = (int*)(wsf + 1024);
    float* wmat = wsf + 1040;

    gap_kernel<<<1024, 256, 0, stream>>>(f0, f1, f2, f3, vecs);
    prep_kernel<<<1, 1024, 0, stream>>>(vecs,
        (const float*)d_in[4], (const float*)d_in[5], (const float*)d_in[6],
        (const float*)d_in[7], (const float*)d_in[8], (const float*)d_in[9],
        order, wmat);

    size_t needA0 = (size_t)HDR * 4 + (size_t)TOTELEM * 4;
    size_t needA1 = needA0 + (size_t)4 * WTOT * 2;   // + bf16 weights (4.7MB)

    if (ws_size >= needA0) {
        // ---- tier A: fp32 G-scheme fusion (grid-stride) -> MFMA conv -> d_out
        float* pyr = wsf + HDR;
        for (int k = 0; k < 4; k++)
            fuse_build_kernel<<<2048, 256, 0, stream>>>(f0, f1, f2, f3,
                                                        pyr, order, wmat, k);
        for (int k = 0; k < 3; k++)
            fuse_final_kernel<<<2048, 256, 0, stream>>>(pyr, order, wmat, k);

        if (ws_size >= needA1) {
            u16* wgtB = (u16*)(pyr + (size_t)TOTELEM);
            wconv_all_kernel<<<(4 * WTOT / 8 + 255) / 256, 256, 0, stream>>>(
                cw[0], cw[1], cw[2], cw[3], wgtB);
            conv_mfma_kernel<true><<<dim3(1, 680), 512, 0, stream>>>(
                pyr, out, cw[0], cw[1], cw[2], cw[3], wgtB,
                cb[0], cb[1], cb[2], cb[3]);
        } else {
            conv_mfma_kernel<false><<<dim3(1, 680), 512, 0, stream>>>(
                pyr, out, cw[0], cw[1], cw[2], cw[3], (const u16*)nullptr,
                cb[0], cb[1], cb[2], cb[3]);
        }
        return;
    }

    if (ws_size >= (size_t)HDR * 4 + 524288) {
        // ---- tier C: fp32 pyramid in d_out; VALU conv via lagged ws strips ----
        float* pyr = out;
        pyr_init_kernel<<<TOTELEM / 256, 256, 0, stream>>>(f0, f1, f2, f3, pyr);
        for (int i = 0; i < 4; i++)
            for (int j = 0; j < 4; j++)
                fuse_step_kernel<<<65536, 256, 0, stream>>>(pyr, order, wmat, i, j);

        float* stageBase = wsf + HDR;
        size_t availF = ws_size / 4 - HDR;
        const int Hs[4] = {256, 128, 64, 32};
        const int logWs[4] = {8, 7, 6, 5};
        const size_t offs[4] = {0, OFF1, OFF2, OFF3};

        for (int l = 0; l < 4; l++) {
            int H = Hs[l], W = H, HW = H * W, logW = logWs[l];
            size_t lvlF = (size_t)HW * 256;
            float* dst = out + offs[l];

            if (availF >= lvlF) {
                conv_strip_kernel<<<dim3(2, HW / 256), 256, 0, stream>>>(
                    dst, stageBase, H, logW, 0, HW, cw[l], cb[l]);
                copyback_kernel<<<(int)((lvlF / 4 + 255) / 256), 256, 0, stream>>>(
                    dst, stageBase, HW, 0, HW);
            } else {
                size_t bufF = availF / 2;
                int alignR = 256 / W; if (alignR < 1) alignR = 1;
                long rowsFit = (long)(bufF / ((size_t)W * 256));
                int R = (int)((rowsFit < (long)H) ? rowsFit : (long)H);
                R -= R % alignR;
                if (R < alignR) R = alignR;
                float* stg[2] = {stageBase, stageBase + bufF};
                int N = (H + R - 1) / R;
                int prPixBase = 0, prPix = 0;
                for (int i = 0; i < N; i++) {
                    int r0 = i * R;
                    int rows = (H - r0 < R) ? (H - r0) : R;
                    int pixB = r0 * W, sp = rows * W;
                    conv_strip_kernel<<<dim3(2, sp / 256), 256, 0, stream>>>(
                        dst, stg[i & 1], H, logW, pixB, sp, cw[l], cb[l]);
                    if (i > 0)
                        copyback_kernel<<<(((prPix >> 2) << 8) + 255) / 256, 256, 0, stream>>>(
                            dst, stg[(i - 1) & 1], prPix, prPixBase, HW);
                    prPixBase = pixB; prPix = sp;
                }
                copyback_kernel<<<(((prPix >> 2) << 8) + 255) / 256, 256, 0, stream>>>(
                    dst, stg[(N - 1) & 1], prPix, prPixBase, HW);
            }
        }
        return;
    }

    // ---- tier D: fuse in d_out + marker (diagnostic) ----
    {
        float* pyr = out;
        pyr_init_kernel<<<TOTELEM / 256, 256, 0, stream>>>(f0, f1, f2, f3, pyr);
        for (int i = 0; i < 4; i++)
            for (int j = 0; j < 4; j++)
                fuse_step_kernel<<<65536, 256, 0, stream>>>(pyr, order, wmat, i, j);
        size_t mb = ws_size >> 20; if (mb > 100) mb = 100;
        marker_kernel<<<1, 64, 0, stream>>>(out, 32768.f + (float)mb * 128.f);
    }
}